// Round 10
// baseline (273.503 us; speedup 1.0000x reference)
//
#include <hip/hip_runtime.h>

// SparseMaxPool — R9 = R8 with the compile fix: __builtin_nontemporal_store
// requires a NATIVE vector type (clang ext_vector_type), not HIP's float4
// class. Theory unchanged: R4/R6/R7 all ~90-96 us kernel time regardless of
// occupancy/LDS traffic -> limiter is dependent store issue (stores gated on
// same-iteration LDS reads). Fix: software-pipeline across tiles (stores
// source from registers loaded LAST iteration; pool/scatter/ds_read of the
// next tile overlaps the store drain) + nontemporal stores (stream past L2
// allocation into the poisoned lines). Structure = R7: persistent 16 KB LDS
// tile zeroed once, direct scatter, mask tiles = all-ones input, one kernel.

typedef float f32x4 __attribute__((ext_vector_type(4)));

constexpr int S_LEN[31] = {
  63,62,61,60,59,58,57,56,55,54,53,52,51,50,49,
  24,23,22,21,20,19,18,17,
  8,7,6,5,4,3,2,1};
constexpr int S_ST[31] = {
  1,1,1,1,1,1,1,1,1,1,1,1,1,1,1,
  2,2,2,2,2,2,2,2,
  4,4,4,4,4,4,4,4};
constexpr int S_OFF[31] = {
  1,2,3,4,5,6,7,8,9,10,11,12,13,14,15,
  17,19,21,23,25,27,29,31,
  35,39,43,47,51,55,59,63};

// Pool chain + direct scatter into the persistent LDS tile (geometry verified
// absmax 0.0 in R4-R7). Wave-synchronous; tile is wave-private.
__device__ __forceinline__ void pool_scatter(float curx, float* tile, int lane) {
  tile[lane * 65] = curx;                   // diagonal
  float cur = curx;
#pragma unroll
  for (int m = 0; m < 31; ++m) {
    if (m == 15 || m == 23) {               // k=3, s=2
      float a = __shfl(cur, 2 * lane);
      float b = __shfl(cur, 2 * lane + 1);
      float c = __shfl(cur, 2 * lane + 2);
      cur = fmaxf(fmaxf(a, b), c);
    } else {                                // k=2, s=1
      cur = fmaxf(cur, __shfl_down(cur, 1));
    }
    if (lane < S_LEN[m]) tile[lane * (S_ST[m] * 65) + S_OFF[m]] = cur;
  }
}

__global__ void __launch_bounds__(64)
sparse_pool_kernel(const float* __restrict__ x, float* __restrict__ out,
                   int nrows, int ntiles) {
  __shared__ float tile[4096];              // 16 KB persistent tile
  const int lane = threadIdx.x;
  const int G = gridDim.x;

  // Zero the tile ONCE; zero background persists across tiles (valid set is
  // tile-invariant and always overwritten).
  const f32x4 z = {0.f, 0.f, 0.f, 0.f};
#pragma unroll
  for (int i = 0; i < 16; ++i)
    ((f32x4*)tile)[i * 64 + lane] = z;

  const f32x4* t4 = (const f32x4*)tile;

  // Prologue: this block's first tile -> LDS -> registers.
  int t = blockIdx.x;                       // grid sized so t < ntiles
  float curx = (t < nrows) ? x[(size_t)t * 64 + lane] : 1.0f;
  pool_scatter(curx, tile, lane);
  f32x4 buf[16];
#pragma unroll
  for (int it = 0; it < 16; ++it) buf[it] = t4[it * 64 + lane];

  for (;;) {
    const int tn = t + G;
    const bool more = tn < ntiles;
    float nxx = 0.f;
    if (more) nxx = (tn < nrows) ? x[(size_t)tn * 64 + lane] : 1.0f;

    // Stores for tile t: register-sourced (no lgkmcnt in the store path),
    // nontemporal, back-to-back.
    f32x4* o4 = (f32x4*)(out + (size_t)t * 4096);
#pragma unroll
    for (int it = 0; it < 16; ++it)
      __builtin_nontemporal_store(buf[it], o4 + it * 64 + lane);

    if (!more) break;

    // Overlap the store drain: compute tile t+G, refill the register buffer.
    pool_scatter(nxx, tile, lane);
#pragma unroll
    for (int it = 0; it < 16; ++it) buf[it] = t4[it * 64 + lane];
    t = tn;
  }
}

extern "C" void kernel_launch(void* const* d_in, const int* in_sizes, int n_in,
                              void* d_out, int out_size, void* d_ws, size_t ws_size,
                              hipStream_t stream) {
  const float* x = (const float*)d_in[0];        // fp32 input (32,512,64)
  float* out = (float*)d_out;                    // fp32 output

  const int nx     = in_sizes[0];                // B*D*64 = 1048576
  const int nrows  = nx / 64;                    // 16384 map tiles
  const int ntiles = out_size / 4096;            // 16448 = map + 32 mask tiles

  // 2056 blocks x 8 tiles each: all resident (16 KB LDS -> 10 blocks/CU
  // capacity vs 8.03 needed), single scheduling round.
  const int blocks = (ntiles + 7) / 8;
  sparse_pool_kernel<<<dim3(blocks), 64, 0, stream>>>(x, out, nrows, ntiles);
}